// Round 7
// baseline (797.419 us; speedup 1.0000x reference)
//
#include <hip/hip_runtime.h>
#include <math.h>

#define Tdim 2048
#define HIDd 1024
#define NHd 16
#define NCOL 4096         // NH*16*16
#define Cn 64             // chunks per sequence
#define Ln 32             // chunk length (Cn*Ln == Tdim)
#define KCAT 3072         // concatenated K: [Ah|Ah/32|Al*32] x [Bh|Bl*32|Bh/32]
#define KB 6144           // KCAT * sizeof(_Float16)
#define KB2 1024          // gemm2 row stride bytes (512 f16)

typedef _Float16 f16x4  __attribute__((ext_vector_type(4)));
typedef _Float16 f16x8  __attribute__((ext_vector_type(8)));
typedef float    f32x4  __attribute__((ext_vector_type(4)));

typedef __attribute__((address_space(1))) void gvoid_t;
typedef __attribute__((address_space(3))) void lvoid_t;

// ---------------- hs (rows x 1024 fp32) -> A_cat (rows x 3072 f16) ------------------------
__global__ __launch_bounds__(256) void conv_A_kernel(const float* __restrict__ hs,
                                                     _Float16* __restrict__ Ac)
{
    const size_t i = ((size_t)blockIdx.x * 256 + threadIdx.x) * 8;
    const size_t r = i >> 10, k = i & 1023;
    const float4 x0 = *(const float4*)(hs + i);
    const float4 x1 = *(const float4*)(hs + i + 4);
    const float v[8] = {x0.x, x0.y, x0.z, x0.w, x1.x, x1.y, x1.z, x1.w};
    f16x8 h, hm, l;
#pragma unroll
    for (int j = 0; j < 8; ++j) {
        const _Float16 hh = (_Float16)v[j];
        h[j]  = hh;
        hm[j] = (_Float16)(v[j] * 0.03125f);          // == hh/32 exactly (pow2 scale)
        l[j]  = (_Float16)((v[j] - (float)hh) * 32.0f);
    }
    _Float16* o = Ac + r * KCAT + k;
    *(f16x8*)(o)        = h;
    *(f16x8*)(o + 1024) = hm;
    *(f16x8*)(o + 2048) = l;
}

// ---------------- W_mat (1024 x 4096 fp32) -> B_cat (4096 x 3072 f16) ---------------------
__global__ __launch_bounds__(256) void conv_B_kernel(const float* __restrict__ W,
                                                     _Float16* __restrict__ Bc)
{
    __shared__ float t[32][33];
    const int tx = threadIdx.x & 31, ty = threadIdx.x >> 5;   // ty 0..7
    const int n0 = blockIdx.x * 32, k0 = blockIdx.y * 32;
#pragma unroll
    for (int i = 0; i < 4; ++i)
        t[ty + i * 8][tx] = W[(size_t)(k0 + ty + i * 8) * NCOL + n0 + tx];
    __syncthreads();
#pragma unroll
    for (int i = 0; i < 4; ++i) {
        const float w = t[tx][ty + i * 8];
        const _Float16 h = (_Float16)w;
        const size_t o = (size_t)(n0 + ty + i * 8) * KCAT + k0 + tx;
        Bc[o]        = h;
        Bc[o + 1024] = (_Float16)((w - (float)h) * 32.0f);
        Bc[o + 2048] = (_Float16)((float)h * 0.03125f);   // exact
    }
}

// ---------------- W_out (512 x 1024 fp32) -> W2T (1024 x 512 fp16) ------------------------
__global__ __launch_bounds__(256) void conv_W2T_kernel(const float* __restrict__ W,
                                                       _Float16* __restrict__ WT)
{
    __shared__ float t[32][33];
    const int tx = threadIdx.x & 31, ty = threadIdx.x >> 5;
    const int n0 = blockIdx.x * 32, k0 = blockIdx.y * 32;
#pragma unroll
    for (int i = 0; i < 4; ++i)
        t[ty + i * 8][tx] = W[(size_t)(k0 + ty + i * 8) * 1024 + n0 + tx];
    __syncthreads();
#pragma unroll
    for (int i = 0; i < 4; ++i)
        WT[(size_t)(n0 + ty + i * 8) * 512 + k0 + tx] = (_Float16)t[tx][ty + i * 8];
}

// ---------------- shared 8-phase GEMM machinery -------------------------------------------
#define MFMA_PHASE(CPH) \
    _Pragma("unroll") \
    for (int m2_ = 0; m2_ < 2; ++m2_) { \
        _Pragma("unroll") \
        for (int nt_ = 0; nt_ < 4; ++nt_) { \
            acc[(CPH)*2 + m2_][nt_] = __builtin_amdgcn_mfma_f32_16x16x32_f16(af[m2_][0], bf[nt_][0], acc[(CPH)*2 + m2_][nt_], 0, 0, 0); \
            acc[(CPH)*2 + m2_][nt_] = __builtin_amdgcn_mfma_f32_16x16x32_f16(af[m2_][1], bf[nt_][1], acc[(CPH)*2 + m2_][nt_], 0, 0, 0); \
        } \
    }

#define PHASE(BUF, CPH, STAGE_EXPR, DOGATE) do { \
    af[0][0] = readA(BUF, (CPH)*2,     0); \
    af[0][1] = readA(BUF, (CPH)*2,     1); \
    af[1][0] = readA(BUF, (CPH)*2 + 1, 0); \
    af[1][1] = readA(BUF, (CPH)*2 + 1, 1); \
    if ((CPH) == 0) { \
        _Pragma("unroll") \
        for (int nt_ = 0; nt_ < 4; ++nt_) { bf[nt_][0] = readB(BUF, nt_, 0); bf[nt_][1] = readB(BUF, nt_, 1); } \
    } \
    STAGE_EXPR; \
    asm volatile("s_barrier" ::: "memory"); \
    asm volatile("s_waitcnt lgkmcnt(0)" ::: "memory"); \
    __builtin_amdgcn_sched_barrier(0); \
    __builtin_amdgcn_s_setprio(1); \
    MFMA_PHASE(CPH) \
    __builtin_amdgcn_s_setprio(0); \
    if (DOGATE) { \
        if (notlast) asm volatile("s_waitcnt vmcnt(6)" ::: "memory"); \
        else         asm volatile("s_waitcnt vmcnt(0)" ::: "memory"); \
    } \
    asm volatile("s_barrier" ::: "memory"); \
} while (0)

// ---------------- GEMM1 + fused stage A: 256x256 tile, 8-phase pipeline -------------------
// After the K-loop, the dead 128 KB staging LDS is reused as a 128x256 f32 half-tile of
// M(+bias). Two phases: waves wm==half dump acc -> barrier -> 8 waves run 8 chunk-chains
// (4 chunks x 2 dirs; arithmetic identical to the r5/r6 passing versions). Chains write
// f16 prefixes over the m buffer (slot t: dir0 bytes 0-511, dir1 512-1023) + q chunk maps.
// Mf uses a (row&4)-keyed 16-float XOR on the column so the acc dump is 2-way (free)
// instead of 4-way bank-conflicting; reads apply the same XOR (bijective per row).
__global__ __launch_bounds__(512, 2) void gemm1_8ph(const _Float16* __restrict__ A,
                                                    const _Float16* __restrict__ B,
                                                    const float* __restrict__ bias,
                                                    float* __restrict__ Mout,
                                                    float* __restrict__ qout, int SS)
{
    __shared__ __align__(16) _Float16 sAB[4][256 * 64];   // [0..1]=A dbuf, [2..3]=B dbuf
    const int tid = threadIdx.x;
    const int lane = tid & 63;
    const int wid = tid >> 6;
    const int wm = wid >> 2, wn = wid & 3;        // wave grid 2 (M) x 4 (N)
    const int q = lane >> 4, ln = lane & 15;
    const int col0 = blockIdx.x * 256;
    const int row0 = blockIdx.y * 256;

    const char* Ab = (const char*)A + (size_t)row0 * KB;
    const char* Bb = (const char*)B + (size_t)col0 * KB;

    auto stage_chunk = [&](const char* g, int fr, int kt, char* ldsbase) {
        const int rr = tid >> 3;
        const int cb = (tid & 7) << 4;
        const char* src = g + (size_t)(fr + rr) * KB + (size_t)kt * 128 + (cb ^ ((rr & 7) << 4));
        char* dst = ldsbase + ((tid >> 6) << 10);
        __builtin_amdgcn_global_load_lds((gvoid_t*)src, (lvoid_t*)dst, 16, 0, 0);
    };
    auto stageA2g = [&](int b, int t, int h) {
        stage_chunk(Ab, h * 64,       t, (char*)&sAB[b][0] + (size_t)(h * 64) * 128);
        stage_chunk(Ab, 128 + h * 64, t, (char*)&sAB[b][0] + (size_t)(128 + h * 64) * 128);
    };
    auto stageB2 = [&](int b, int t, int h) {
        stage_chunk(Bb, h * 128,      t, (char*)&sAB[2 + b][0] + (size_t)(h * 128) * 128);
        stage_chunk(Bb, h * 128 + 64, t, (char*)&sAB[2 + b][0] + (size_t)(h * 128 + 64) * 128);
    };
    auto readA = [&](int b, int mf, int ks) -> f16x8 {
        const int r = wm * 128 + mf * 16 + ln;
        return *(const f16x8*)((const char*)&sAB[b][0] + r * 128 + ((ks * 64 + q * 16) ^ ((r & 7) << 4)));
    };
    auto readB = [&](int b, int nt, int ks) -> f16x8 {
        const int r = wn * 64 + nt * 16 + ln;
        return *(const f16x8*)((const char*)&sAB[2 + b][0] + r * 128 + ((ks * 64 + q * 16) ^ ((r & 7) << 4)));
    };

    stageB2(0, 0, 0); stageB2(0, 0, 1); stageA2g(0, 0, 0); stageA2g(0, 0, 1);
    stageB2(1, 1, 0); stageB2(1, 1, 1); stageA2g(1, 1, 0);

    f32x4 acc[8][4];
    const f32x4 z4 = {0.f, 0.f, 0.f, 0.f};
#pragma unroll
    for (int mf = 0; mf < 8; ++mf)
#pragma unroll
        for (int nt = 0; nt < 4; ++nt) acc[mf][nt] = z4;

    asm volatile("s_waitcnt vmcnt(6)" ::: "memory");
    asm volatile("s_barrier" ::: "memory");

    f16x8 af[2][2];
    f16x8 bf[4][2];

#pragma unroll 1
    for (int it = 0; it < 24; ++it) {
        const int t0 = it * 2;
        const bool notlast = (it != 23);
        PHASE(0, 0, (stageA2g(1, t0 + 1, 1)), 0);
        PHASE(0, 1, (notlast ? stageB2(0, t0 + 2, 0) : (void)0), 0);
        PHASE(0, 2, (notlast ? stageB2(0, t0 + 2, 1) : (void)0), 0);
        PHASE(0, 3, (notlast ? stageA2g(0, t0 + 2, 0) : (void)0), 1);
        PHASE(1, 0, (notlast ? stageA2g(0, t0 + 2, 1) : (void)0), 0);
        PHASE(1, 1, (notlast ? stageB2(1, t0 + 3, 0) : (void)0), 0);
        PHASE(1, 2, (notlast ? stageB2(1, t0 + 3, 1) : (void)0), 0);
        PHASE(1, 3, (notlast ? stageA2g(1, t0 + 3, 0) : (void)0), 1);
    }

    // ---------------- fused stage A epilogue ----------------
    float* Mf = (float*)&sAB[0][0];               // 128 x 256 f32 half-tile (128 KB)
    const int seq = ((row0 >> 11) << 4) + blockIdx.x;   // bbl*16 + head
    const int cc   = wid & 3;                     // chunk-in-half
    const int dirw = wid >> 2;                    // 0 = lr, 1 = rl
    float bv[4];
#pragma unroll
    for (int nt = 0; nt < 4; ++nt) bv[nt] = bias[col0 + wn * 64 + nt * 16 + ln];

#pragma unroll 1
    for (int half = 0; half < 2; ++half) {
        __syncthreads();                          // LDS free / prev-phase readers done
        if (wm == half) {
#pragma unroll
            for (int mf = 0; mf < 8; ++mf)
#pragma unroll
                for (int nt = 0; nt < 4; ++nt)
#pragma unroll
                    for (int r = 0; r < 4; ++r) {
                        const int mrow = mf * 16 + q * 4 + r;
                        const int mcol = (wn * 64 + nt * 16 + ln) ^ ((mrow & 4) << 2);
                        Mf[mrow * 256 + mcol] = acc[mf][nt][r] + bv[nt];
                    }
        }
        __syncthreads();

        const int cblk = half * 4 + cc;           // chunk 0..7 within block
        const int tb   = cblk * 32 - half * 128;  // local row base in Mf
        float v[4];
#pragma unroll
        for (int r = 0; r < 4; ++r) v[r] = (q * 4 + r == ln) ? 1.0f : 0.0f;

        int tl = dirw ? (tb + 31) : tb;
        const int ds = dirw ? -1 : 1;
        float4 arow = *(const float4*)&Mf[tl * 256 + ((ln * 16 + q * 4) ^ ((tl & 4) << 2))];
        float f2 = arow.x*arow.x + arow.y*arow.y + arow.z*arow.z + arow.w*arow.w;
#pragma unroll
        for (int off = 1; off < 64; off <<= 1) f2 += __shfl_xor(f2, off);
        float sm = 4.0f * rsqrtf(f2 + 1e-12f);

        for (int s = 0; s < Ln; ++s) {
            const int tabs = (row0 & 2047) + (dirw ? (cblk * 32 + 31 - s) : (cblk * 32 + s));
            // split sm-scaled M row fragment (hi + lo*1024)
            f16x4 mh, mlo;
            const float ar[4] = {arow.x * sm, arow.y * sm, arow.z * sm, arow.w * sm};
#pragma unroll
            for (int i = 0; i < 4; ++i) {
                const _Float16 h = (_Float16)ar[i];
                mh[i] = h; mlo[i] = (_Float16)((ar[i] - (float)h) * 1024.0f);
            }
            // next M row + its f2/sm chain overlaps this step's MFMA chain
            float smn = sm;
            if (s + 1 < Ln) {
                tl += ds;
                arow = *(const float4*)&Mf[tl * 256 + ((ln * 16 + q * 4) ^ ((tl & 4) << 2))];
                float f2n = arow.x*arow.x + arow.y*arow.y + arow.z*arow.z + arow.w*arow.w;
#pragma unroll
                for (int off = 1; off < 64; off <<= 1) f2n += __shfl_xor(f2n, off);
                smn = 4.0f * rsqrtf(f2n + 1e-12f);
            }
            // split running product (hi + lo*1024)
            f16x4 qh, ql;
#pragma unroll
            for (int r = 0; r < 4; ++r) {
                const _Float16 h = (_Float16)v[r];
                qh[r] = h; ql[r] = (_Float16)((v[r] - (float)h) * 1024.0f);
            }
            f32x4 a1 = {0.f,0.f,0.f,0.f}, a2 = {0.f,0.f,0.f,0.f};
            a1 = __builtin_amdgcn_mfma_f32_16x16x16f16(mh,  qh, a1, 0, 0, 0);
            a2 = __builtin_amdgcn_mfma_f32_16x16x16f16(mh,  ql, a2, 0, 0, 0);
            a2 = __builtin_amdgcn_mfma_f32_16x16x16f16(mlo, qh, a2, 0, 0, 0);
#pragma unroll
            for (int r = 0; r < 4; ++r) v[r] = a1[r] + a2[r] * (1.0f / 1024.0f);

            if (s & 1) {                          // rescale every 2nd step (value arbitrary)
                float mx = 0.f;
#pragma unroll
                for (int r = 0; r < 4; ++r) mx = fmaxf(mx, fabsf(v[r]));
#pragma unroll
                for (int off = 1; off < 64; off <<= 1) mx = fmaxf(mx, __shfl_xor(mx, off));
                const float inv = 1.0f / (mx + 1e-30f);
#pragma unroll
                for (int r = 0; r < 4; ++r) v[r] *= inv;
            }
            // prefix store (f16) over m slot tabs (stageC2 normalizes -> scale free)
            _Float16* Pp = (_Float16*)((char*)Mout
                         + ((size_t)seq * Tdim + tabs) * 1024 + dirw * 512);
#pragma unroll
            for (int r = 0; r < 4; ++r)
                Pp[(q * 4 + r) * 16 + ln] = (_Float16)v[r];
            sm = smn;
        }

        // final L2 normalize + chunk map for stageB
        float ss = 0.f;
#pragma unroll
        for (int r = 0; r < 4; ++r) ss += v[r] * v[r];
#pragma unroll
        for (int off = 1; off < 64; off <<= 1) ss += __shfl_xor(ss, off);
        const float sl = 1.0f / (sqrtf(ss) + 1e-30f);
        const int cabs = ((row0 & 2047) >> 5) + cblk;
        float* qo = qout + ((size_t)(dirw * SS + seq) * Cn + cabs) * 256;
#pragma unroll
        for (int r = 0; r < 4; ++r)
            qo[(q * 4 + r) * 16 + ln] = v[r] * sl;
    }
}

// ---------------- Stage B: cross-chunk vector propagation (r3-proven) ---------------------
__global__ __launch_bounds__(64) void stageB_kernel(const float* __restrict__ q,
                                                    float* __restrict__ vs, int SS)
{
    const int lane = threadIdx.x & 63;
    const int i = lane & 15;
    const int chain = blockIdx.x;
    const int dir = (chain >= SS) ? 1 : 0;
    const int seq = chain - dir * SS;
    const float* qb = q + (size_t)(dir * SS + seq) * Cn * 256;
    float* vb = vs + (size_t)(dir * SS + seq) * Cn * 16;

    float myw = (i == 0) ? 1.0f : 0.0f;
    float wv[16];
#pragma unroll
    for (int k2 = 0; k2 < 16; ++k2) wv[k2] = (k2 == 0) ? 1.0f : 0.0f;

    int cc = dir ? (Cn - 1) : 0;
    const float* Qp = qb + (size_t)cc * 256 + i * 16;
    float4 q0 = *(const float4*)(Qp + 0);
    float4 q1 = *(const float4*)(Qp + 4);
    float4 q2 = *(const float4*)(Qp + 8);
    float4 q3 = *(const float4*)(Qp + 12);

    for (int s = 0; s < Cn; ++s) {
        vb[cc * 16 + i] = myw;
        float nv = q0.x*wv[0] + q0.y*wv[1] + q0.z*wv[2] + q0.w*wv[3]
                 + q1.x*wv[4] + q1.y*wv[5] + q1.z*wv[6] + q1.w*wv[7]
                 + q2.x*wv[8] + q2.y*wv[9] + q2.z*wv[10] + q2.w*wv[11]
                 + q3.x*wv[12] + q3.y*wv[13] + q3.z*wv[14] + q3.w*wv[15];
        if (s + 1 < Cn) {                       // prefetch next chunk's Q
            const int ccn = dir ? (Cn - 2 - s) : (s + 1);
            const float* Qn = qb + (size_t)ccn * 256 + i * 16;
            q0 = *(const float4*)(Qn + 0);
            q1 = *(const float4*)(Qn + 4);
            q2 = *(const float4*)(Qn + 8);
            q3 = *(const float4*)(Qn + 12);
        }
        float s2 = nv * nv;
        s2 += __shfl_xor(s2, 1); s2 += __shfl_xor(s2, 2);
        s2 += __shfl_xor(s2, 4); s2 += __shfl_xor(s2, 8);
        const float wn = nv / (sqrtf(s2) + 1e-20f);
        myw = wn;
#pragma unroll
        for (int k2 = 0; k2 < 16; ++k2) wv[k2] = __shfl(wn, (lane & 48) | k2);
        cc = dir ? (Cn - 2 - s) : (s + 1);
    }
}

// ---------------- Stage C2: parallel replay x_t = normalize(P_t . v_start) ----------------
__global__ __launch_bounds__(256) void stageC2_kernel(const float* __restrict__ m,
                                                      const float* __restrict__ vs,
                                                      _Float16* __restrict__ x, int SS)
{
    const int tid = threadIdx.x;
    const int wave = tid >> 6, lane = tid & 63;
    const int dsc = blockIdx.x * 4 + wave;        // (dir*SS + seq)*Cn + c
    const int dirseq = dsc >> 6, c = dsc & (Cn - 1);
    const int dir = (dirseq >= SS) ? 1 : 0;
    const int seq = dirseq - dir * SS;
    const int bbl = seq >> 4, h = seq & 15;
    const _Float16* Pp = (const _Float16*)((const char*)m
                       + ((size_t)seq * Tdim + c * Ln) * 1024 + dir * 512);
    const float* vp = vs + (size_t)dsc * 16;

    float v[16];
#pragma unroll
    for (int k = 0; k < 16; ++k) v[k] = vp[k];    // wave-uniform -> broadcast loads

    const int tt = lane >> 4, j = lane & 15;
    const int t0 = c * Ln;
#pragma unroll
    for (int g = 0; g < 8; ++g) {
        const int s = g * 4 + tt;
        const _Float16* pr = Pp + (size_t)s * 512 + j * 16;   // slot stride 1024 B = 512 f16
        const f16x8 p0 = *(const f16x8*)(pr);
        const f16x8 p1 = *(const f16x8*)(pr + 8);
        float nv = 0.f;
#pragma unroll
        for (int k = 0; k < 8; ++k) nv += (float)p0[k] * v[k];
#pragma unroll
        for (int k = 0; k < 8; ++k) nv += (float)p1[k] * v[k + 8];
        float s2 = nv * nv;
        s2 += __shfl_xor(s2, 1); s2 += __shfl_xor(s2, 2);
        s2 += __shfl_xor(s2, 4); s2 += __shfl_xor(s2, 8);
        const float vn = nv / (sqrtf(s2) + 1e-6f);   // reference VEC_EPS semantics
        const int t = t0 + s;                        // slot t holds prefix for output t (both dirs)
        x[(((size_t)bbl * Tdim + t) * NHd + h) * 32 + dir * 16 + j] = (_Float16)vn;
    }
}

// ---------------- GEMM2: 256x256 tile, K=512, same 8-phase counted-vmcnt pipeline ---------
__global__ __launch_bounds__(512, 2) void gemm2_8ph(const _Float16* __restrict__ A,
                                                    const _Float16* __restrict__ BT,
                                                    const float* __restrict__ bias,
                                                    float* __restrict__ out, int row0p)
{
    __shared__ __align__(16) _Float16 sAB[4][256 * 64];   // [0..1]=A dbuf, [2..3]=B dbuf
    const int tid = threadIdx.x;
    const int lane = tid & 63;
    const int wid = tid >> 6;
    const int wm = wid >> 2, wn = wid & 3;
    const int q = lane >> 4, ln = lane & 15;
    const int col0 = blockIdx.x * 256;
    const int row0 = blockIdx.y * 256;

    const char* Ab = (const char*)A  + (size_t)row0 * KB2;
    const char* Bb = (const char*)BT + (size_t)col0 * KB2;

    auto stage_chunk = [&](const char* g, int fr, int kt, char* ldsbase) {
        const int rr = tid >> 3;
        const int cb = (tid & 7) << 4;
        const char* src = g + (size_t)(fr + rr) * KB2 + (size_t)kt * 128 + (cb ^ ((rr & 7) << 4));
        char* dst = ldsbase + ((tid >> 6) << 10);
        __builtin_amdgcn_global_load_lds((gvoid_t*)src, (lvoid_t*)dst, 16, 0, 0);
    };
    auto stageA2g = [&](int b, int t, int h) {
        stage_chunk(Ab, h * 64,       t, (char*)&sAB[b][0] + (size_t)(h * 64) * 128);
        stage_chunk(Ab, 128 + h * 64, t, (char*)&sAB[b][0] + (size_t)(128 + h * 64) * 128);
    };
    auto stageB2 = [&](int b, int t, int h) {
        stage_chunk(Bb, h * 128,      t, (char*)&sAB[2 + b][0] + (size_t)(h * 128) * 128);
        stage_chunk(Bb, h * 128 + 64, t, (char*)&sAB[2 + b][0] + (size_t)(h * 128 + 64) * 128);
    };
    auto readA = [&](int b, int mf, int ks) -> f16x8 {
        const int r = wm * 128 + mf * 16 + ln;
        return *(const f16x8*)((const char*)&sAB[b][0] + r * 128 + ((ks * 64 + q * 16) ^ ((r & 7) << 4)));
    };
    auto readB = [&](int b, int nt, int ks) -> f16x8 {
        const int r = wn * 64 + nt * 16 + ln;
        return *(const f16x8*)((const char*)&sAB[2 + b][0] + r * 128 + ((ks * 64 + q * 16) ^ ((r & 7) << 4)));
    };

    stageB2(0, 0, 0); stageB2(0, 0, 1); stageA2g(0, 0, 0); stageA2g(0, 0, 1);
    stageB2(1, 1, 0); stageB2(1, 1, 1); stageA2g(1, 1, 0);

    f32x4 acc[8][4];
    const f32x4 z4 = {0.f, 0.f, 0.f, 0.f};
#pragma unroll
    for (int mf = 0; mf < 8; ++mf)
#pragma unroll
        for (int nt = 0; nt < 4; ++nt) acc[mf][nt] = z4;

    asm volatile("s_waitcnt vmcnt(6)" ::: "memory");
    asm volatile("s_barrier" ::: "memory");

    f16x8 af[2][2];
    f16x8 bf[4][2];

#pragma unroll 1
    for (int it = 0; it < 4; ++it) {              // K = 512 -> 8 tiles of 64 -> 4 iters
        const int t0 = it * 2;
        const bool notlast = (it != 3);
        PHASE(0, 0, (stageA2g(1, t0 + 1, 1)), 0);
        PHASE(0, 1, (notlast ? stageB2(0, t0 + 2, 0) : (void)0), 0);
        PHASE(0, 2, (notlast ? stageB2(0, t0 + 2, 1) : (void)0), 0);
        PHASE(0, 3, (notlast ? stageA2g(0, t0 + 2, 0) : (void)0), 1);
        PHASE(1, 0, (notlast ? stageA2g(0, t0 + 2, 1) : (void)0), 0);
        PHASE(1, 1, (notlast ? stageB2(1, t0 + 3, 0) : (void)0), 0);
        PHASE(1, 2, (notlast ? stageB2(1, t0 + 3, 1) : (void)0), 0);
        PHASE(1, 3, (notlast ? stageA2g(1, t0 + 3, 0) : (void)0), 1);
    }

#pragma unroll
    for (int nt = 0; nt < 4; ++nt) {
        const int c = col0 + wn * 64 + nt * 16 + ln;
        const float bv = bias[c];
#pragma unroll
        for (int mf = 0; mf < 8; ++mf) {
#pragma unroll
            for (int r = 0; r < 4; ++r) {
                const int row = row0 + wm * 128 + mf * 16 + q * 4 + r;
                float v = acc[mf][nt][r] + bv;
                v = 0.5f * v * (1.0f + erff(v * 0.70710678118654752f));
                out[(size_t)(row0p + row) * 1024 + c] = v;
            }
        }
    }
}

extern "C" void kernel_launch(void* const* d_in, const int* in_sizes, int n_in,
                              void* d_out, int out_size, void* d_ws, size_t ws_size,
                              hipStream_t stream)
{
    const float* hs    = (const float*)d_in[0];
    const float* W_mat = (const float*)d_in[1];
    const float* b_mat = (const float*)d_in[2];
    const float* W_out = (const float*)d_in[3];
    const float* b_out = (const float*)d_in[4];
    float* out = (float*)d_out;

    // layout: W2T(1M) Bcat(24M) | per bb-group: m 32M (f16 prefixes, written by gemm1) |
    //         qx 2M (q f32 / x f16 aliased) | Acat 12M | vs 128K
    const size_t per_bb = (32ull << 20) + (2ull << 20) + (12ull << 20) + (128ull << 10);
    const size_t wbase  = 25ull << 20;
    int nbb = 8;
    while (nbb > 1 && ws_size < wbase + (size_t)nbb * per_bb) nbb >>= 1;

    char* base = (char*)d_ws;
    _Float16* W2T = (_Float16*)base;
    _Float16* Bc  = (_Float16*)(base + (1ull << 20));
    size_t off = wbase;
    float* m  = (float*)(base + off);  off += (size_t)nbb * (32ull << 20);
    float* qx = (float*)(base + off);  off += (size_t)nbb * (2ull << 20);
    _Float16* Ac = (_Float16*)(base + off); off += (size_t)nbb * (12ull << 20);
    float* vs = (float*)(base + off);

    conv_B_kernel<<<dim3(128, 32), 256, 0, stream>>>(W_mat, Bc);
    conv_W2T_kernel<<<dim3(32, 16), 256, 0, stream>>>(W_out, W2T);

    for (int bb0 = 0; bb0 < 8; bb0 += nbb) {
        const int row0 = bb0 * Tdim;
        const int SS = nbb * 16;
        conv_A_kernel<<<nbb * 1024, 256, 0, stream>>>(hs + (size_t)row0 * HIDd, Ac);
        gemm1_8ph<<<dim3(16, nbb * 8), 512, 0, stream>>>(Ac, Bc, b_mat, m, qx, SS);
        stageB_kernel<<<2 * SS, 64, 0, stream>>>(qx, vs, SS);
        stageC2_kernel<<<SS * Cn / 2, 256, 0, stream>>>(m, vs, (_Float16*)qx, SS);
        gemm2_8ph<<<dim3(4, nbb * 8), 512, 0, stream>>>((_Float16*)qx, W2T, b_out, out, row0);
    }
}

// Round 9
// 794.475 us; speedup vs baseline: 1.0037x; 1.0037x over previous
//
#include <hip/hip_runtime.h>
#include <math.h>

#define Tdim 2048
#define HIDd 1024
#define NHd 16
#define NCOL 4096         // NH*16*16
#define Cn 64             // chunks per sequence
#define Ln 32             // chunk length (Cn*Ln == Tdim)
#define KCAT 3072         // concatenated K: [Ah|Ah/32|Al*32] x [Bh|Bl*32|Bh/32]
#define KB 6144           // KCAT * sizeof(_Float16)
#define KB2 1024          // gemm2 row stride bytes (512 f16)

typedef _Float16 f16x4  __attribute__((ext_vector_type(4)));
typedef _Float16 f16x8  __attribute__((ext_vector_type(8)));
typedef float    f32x4  __attribute__((ext_vector_type(4)));

typedef __attribute__((address_space(1))) void gvoid_t;
typedef __attribute__((address_space(3))) void lvoid_t;

// ---------------- hs (rows x 1024 fp32) -> A_cat (rows x 3072 f16) ------------------------
__global__ __launch_bounds__(256) void conv_A_kernel(const float* __restrict__ hs,
                                                     _Float16* __restrict__ Ac)
{
    const size_t i = ((size_t)blockIdx.x * 256 + threadIdx.x) * 8;
    const size_t r = i >> 10, k = i & 1023;
    const float4 x0 = *(const float4*)(hs + i);
    const float4 x1 = *(const float4*)(hs + i + 4);
    const float v[8] = {x0.x, x0.y, x0.z, x0.w, x1.x, x1.y, x1.z, x1.w};
    f16x8 h, hm, l;
#pragma unroll
    for (int j = 0; j < 8; ++j) {
        const _Float16 hh = (_Float16)v[j];
        h[j]  = hh;
        hm[j] = (_Float16)(v[j] * 0.03125f);          // == hh/32 exactly (pow2 scale)
        l[j]  = (_Float16)((v[j] - (float)hh) * 32.0f);
    }
    _Float16* o = Ac + r * KCAT + k;
    *(f16x8*)(o)        = h;
    *(f16x8*)(o + 1024) = hm;
    *(f16x8*)(o + 2048) = l;
}

// ---------------- W_mat (1024 x 4096 fp32) -> B_cat (4096 x 3072 f16) ---------------------
__global__ __launch_bounds__(256) void conv_B_kernel(const float* __restrict__ W,
                                                     _Float16* __restrict__ Bc)
{
    __shared__ float t[32][33];
    const int tx = threadIdx.x & 31, ty = threadIdx.x >> 5;   // ty 0..7
    const int n0 = blockIdx.x * 32, k0 = blockIdx.y * 32;
#pragma unroll
    for (int i = 0; i < 4; ++i)
        t[ty + i * 8][tx] = W[(size_t)(k0 + ty + i * 8) * NCOL + n0 + tx];
    __syncthreads();
#pragma unroll
    for (int i = 0; i < 4; ++i) {
        const float w = t[tx][ty + i * 8];
        const _Float16 h = (_Float16)w;
        const size_t o = (size_t)(n0 + ty + i * 8) * KCAT + k0 + tx;
        Bc[o]        = h;
        Bc[o + 1024] = (_Float16)((w - (float)h) * 32.0f);
        Bc[o + 2048] = (_Float16)((float)h * 0.03125f);   // exact
    }
}

// ---------------- W_out (512 x 1024 fp32) -> W2T (1024 x 512 fp16) ------------------------
__global__ __launch_bounds__(256) void conv_W2T_kernel(const float* __restrict__ W,
                                                       _Float16* __restrict__ WT)
{
    __shared__ float t[32][33];
    const int tx = threadIdx.x & 31, ty = threadIdx.x >> 5;
    const int n0 = blockIdx.x * 32, k0 = blockIdx.y * 32;
#pragma unroll
    for (int i = 0; i < 4; ++i)
        t[ty + i * 8][tx] = W[(size_t)(k0 + ty + i * 8) * 1024 + n0 + tx];
    __syncthreads();
#pragma unroll
    for (int i = 0; i < 4; ++i)
        WT[(size_t)(n0 + ty + i * 8) * 512 + k0 + tx] = (_Float16)t[tx][ty + i * 8];
}

// ---------------- shared 8-phase GEMM machinery -------------------------------------------
#define MFMA_PHASE(CPH) \
    _Pragma("unroll") \
    for (int m2_ = 0; m2_ < 2; ++m2_) { \
        _Pragma("unroll") \
        for (int nt_ = 0; nt_ < 4; ++nt_) { \
            acc[(CPH)*2 + m2_][nt_] = __builtin_amdgcn_mfma_f32_16x16x32_f16(af[m2_][0], bf[nt_][0], acc[(CPH)*2 + m2_][nt_], 0, 0, 0); \
            acc[(CPH)*2 + m2_][nt_] = __builtin_amdgcn_mfma_f32_16x16x32_f16(af[m2_][1], bf[nt_][1], acc[(CPH)*2 + m2_][nt_], 0, 0, 0); \
        } \
    }

#define PHASE(BUF, CPH, STAGE_EXPR, DOGATE) do { \
    af[0][0] = readA(BUF, (CPH)*2,     0); \
    af[0][1] = readA(BUF, (CPH)*2,     1); \
    af[1][0] = readA(BUF, (CPH)*2 + 1, 0); \
    af[1][1] = readA(BUF, (CPH)*2 + 1, 1); \
    if ((CPH) == 0) { \
        _Pragma("unroll") \
        for (int nt_ = 0; nt_ < 4; ++nt_) { bf[nt_][0] = readB(BUF, nt_, 0); bf[nt_][1] = readB(BUF, nt_, 1); } \
    } \
    STAGE_EXPR; \
    asm volatile("s_barrier" ::: "memory"); \
    asm volatile("s_waitcnt lgkmcnt(0)" ::: "memory"); \
    __builtin_amdgcn_sched_barrier(0); \
    __builtin_amdgcn_s_setprio(1); \
    MFMA_PHASE(CPH) \
    __builtin_amdgcn_s_setprio(0); \
    if (DOGATE) { \
        if (notlast) asm volatile("s_waitcnt vmcnt(6)" ::: "memory"); \
        else         asm volatile("s_waitcnt vmcnt(0)" ::: "memory"); \
    } \
    asm volatile("s_barrier" ::: "memory"); \
} while (0)

// ---------------- GEMM1 + fused stage A: 256x256 tile, 8-phase pipeline -------------------
__global__ __launch_bounds__(512, 2) void gemm1_8ph(const _Float16* __restrict__ A,
                                                    const _Float16* __restrict__ B,
                                                    const float* __restrict__ bias,
                                                    float* __restrict__ Mout,
                                                    float* __restrict__ qout, int SS)
{
    __shared__ __align__(16) _Float16 sAB[4][256 * 64];   // [0..1]=A dbuf, [2..3]=B dbuf
    const int tid = threadIdx.x;
    const int lane = tid & 63;
    const int wid = tid >> 6;
    const int wm = wid >> 2, wn = wid & 3;        // wave grid 2 (M) x 4 (N)
    const int q = lane >> 4, ln = lane & 15;
    const int col0 = blockIdx.x * 256;
    const int row0 = blockIdx.y * 256;

    const char* Ab = (const char*)A + (size_t)row0 * KB;
    const char* Bb = (const char*)B + (size_t)col0 * KB;

    auto stage_chunk = [&](const char* g, int fr, int kt, char* ldsbase) {
        const int rr = tid >> 3;
        const int cb = (tid & 7) << 4;
        const char* src = g + (size_t)(fr + rr) * KB + (size_t)kt * 128 + (cb ^ ((rr & 7) << 4));
        char* dst = ldsbase + ((tid >> 6) << 10);
        __builtin_amdgcn_global_load_lds((gvoid_t*)src, (lvoid_t*)dst, 16, 0, 0);
    };
    auto stageA2g = [&](int b, int t, int h) {
        stage_chunk(Ab, h * 64,       t, (char*)&sAB[b][0] + (size_t)(h * 64) * 128);
        stage_chunk(Ab, 128 + h * 64, t, (char*)&sAB[b][0] + (size_t)(128 + h * 64) * 128);
    };
    auto stageB2 = [&](int b, int t, int h) {
        stage_chunk(Bb, h * 128,      t, (char*)&sAB[2 + b][0] + (size_t)(h * 128) * 128);
        stage_chunk(Bb, h * 128 + 64, t, (char*)&sAB[2 + b][0] + (size_t)(h * 128 + 64) * 128);
    };
    auto readA = [&](int b, int mf, int ks) -> f16x8 {
        const int r = wm * 128 + mf * 16 + ln;
        return *(const f16x8*)((const char*)&sAB[b][0] + r * 128 + ((ks * 64 + q * 16) ^ ((r & 7) << 4)));
    };
    auto readB = [&](int b, int nt, int ks) -> f16x8 {
        const int r = wn * 64 + nt * 16 + ln;
        return *(const f16x8*)((const char*)&sAB[2 + b][0] + r * 128 + ((ks * 64 + q * 16) ^ ((r & 7) << 4)));
    };

    stageB2(0, 0, 0); stageB2(0, 0, 1); stageA2g(0, 0, 0); stageA2g(0, 0, 1);
    stageB2(1, 1, 0); stageB2(1, 1, 1); stageA2g(1, 1, 0);

    f32x4 acc[8][4];
    const f32x4 z4 = {0.f, 0.f, 0.f, 0.f};
#pragma unroll
    for (int mf = 0; mf < 8; ++mf)
#pragma unroll
        for (int nt = 0; nt < 4; ++nt) acc[mf][nt] = z4;

    asm volatile("s_waitcnt vmcnt(6)" ::: "memory");
    asm volatile("s_barrier" ::: "memory");

    f16x8 af[2][2];
    f16x8 bf[4][2];

#pragma unroll 1
    for (int it = 0; it < 24; ++it) {
        const int t0 = it * 2;
        const bool notlast = (it != 23);
        PHASE(0, 0, (stageA2g(1, t0 + 1, 1)), 0);
        PHASE(0, 1, (notlast ? stageB2(0, t0 + 2, 0) : (void)0), 0);
        PHASE(0, 2, (notlast ? stageB2(0, t0 + 2, 1) : (void)0), 0);
        PHASE(0, 3, (notlast ? stageA2g(0, t0 + 2, 0) : (void)0), 1);
        PHASE(1, 0, (notlast ? stageA2g(0, t0 + 2, 1) : (void)0), 0);
        PHASE(1, 1, (notlast ? stageB2(1, t0 + 3, 0) : (void)0), 0);
        PHASE(1, 2, (notlast ? stageB2(1, t0 + 3, 1) : (void)0), 0);
        PHASE(1, 3, (notlast ? stageA2g(1, t0 + 3, 0) : (void)0), 1);
    }

    // ---------------- fused stage A epilogue ----------------
    float* Mf = (float*)&sAB[0][0];               // 128 x 256 f32 half-tile (128 KB)
    const int seq = ((row0 >> 11) << 4) + blockIdx.x;   // bbl*16 + head
    const int cc   = wid & 3;                     // chunk-in-half
    const int dirw = wid >> 2;                    // 0 = lr, 1 = rl
    float bv[4];
#pragma unroll
    for (int nt = 0; nt < 4; ++nt) bv[nt] = bias[col0 + wn * 64 + nt * 16 + ln];

#pragma unroll 1
    for (int half = 0; half < 2; ++half) {
        __syncthreads();                          // LDS free / prev-phase readers done
        if (wm == half) {
#pragma unroll
            for (int mf = 0; mf < 8; ++mf)
#pragma unroll
                for (int nt = 0; nt < 4; ++nt)
#pragma unroll
                    for (int r = 0; r < 4; ++r) {
                        const int mrow = mf * 16 + q * 4 + r;
                        const int mcol = (wn * 64 + nt * 16 + ln) ^ ((mrow & 4) << 2);
                        Mf[mrow * 256 + mcol] = acc[mf][nt][r] + bv[nt];
                    }
        }
        __syncthreads();

        const int cblk = half * 4 + cc;           // chunk 0..7 within block
        const int tb   = cblk * 32 - half * 128;  // local row base in Mf
        float v[4];
#pragma unroll
        for (int r = 0; r < 4; ++r) v[r] = (q * 4 + r == ln) ? 1.0f : 0.0f;

        int tl = dirw ? (tb + 31) : tb;
        const int ds = dirw ? -1 : 1;
        float4 arow = *(const float4*)&Mf[tl * 256 + ((ln * 16 + q * 4) ^ ((tl & 4) << 2))];
        float f2 = arow.x*arow.x + arow.y*arow.y + arow.z*arow.z + arow.w*arow.w;
#pragma unroll
        for (int off = 1; off < 64; off <<= 1) f2 += __shfl_xor(f2, off);
        float sm = 4.0f * rsqrtf(f2 + 1e-12f);

        for (int s = 0; s < Ln; ++s) {
            const int tabs = (row0 & 2047) + (dirw ? (cblk * 32 + 31 - s) : (cblk * 32 + s));
            // split sm-scaled M row fragment (hi + lo*1024)
            f16x4 mh, mlo;
            const float ar[4] = {arow.x * sm, arow.y * sm, arow.z * sm, arow.w * sm};
#pragma unroll
            for (int i = 0; i < 4; ++i) {
                const _Float16 h = (_Float16)ar[i];
                mh[i] = h; mlo[i] = (_Float16)((ar[i] - (float)h) * 1024.0f);
            }
            // next M row + its f2/sm chain overlaps this step's MFMA chain
            float smn = sm;
            if (s + 1 < Ln) {
                tl += ds;
                arow = *(const float4*)&Mf[tl * 256 + ((ln * 16 + q * 4) ^ ((tl & 4) << 2))];
                float f2n = arow.x*arow.x + arow.y*arow.y + arow.z*arow.z + arow.w*arow.w;
#pragma unroll
                for (int off = 1; off < 64; off <<= 1) f2n += __shfl_xor(f2n, off);
                smn = 4.0f * rsqrtf(f2n + 1e-12f);
            }
            // split running product (hi + lo*1024)
            f16x4 qh, ql;
#pragma unroll
            for (int r = 0; r < 4; ++r) {
                const _Float16 h = (_Float16)v[r];
                qh[r] = h; ql[r] = (_Float16)((v[r] - (float)h) * 1024.0f);
            }
            f32x4 a1 = {0.f,0.f,0.f,0.f}, a2 = {0.f,0.f,0.f,0.f};
            a1 = __builtin_amdgcn_mfma_f32_16x16x16f16(mh,  qh, a1, 0, 0, 0);
            a2 = __builtin_amdgcn_mfma_f32_16x16x16f16(mh,  ql, a2, 0, 0, 0);
            a2 = __builtin_amdgcn_mfma_f32_16x16x16f16(mlo, qh, a2, 0, 0, 0);
#pragma unroll
            for (int r = 0; r < 4; ++r) v[r] = a1[r] + a2[r] * (1.0f / 1024.0f);

            if (s & 1) {                          // rescale every 2nd step (value arbitrary)
                float mx = 0.f;
#pragma unroll
                for (int r = 0; r < 4; ++r) mx = fmaxf(mx, fabsf(v[r]));
#pragma unroll
                for (int off = 1; off < 64; off <<= 1) mx = fmaxf(mx, __shfl_xor(mx, off));
                const float inv = 1.0f / (mx + 1e-30f);
#pragma unroll
                for (int r = 0; r < 4; ++r) v[r] *= inv;
            }
            // prefix store (f16) over m slot tabs (stageC2 normalizes -> scale free)
            _Float16* Pp = (_Float16*)((char*)Mout
                         + ((size_t)seq * Tdim + tabs) * 1024 + dirw * 512);
#pragma unroll
            for (int r = 0; r < 4; ++r)
                Pp[(q * 4 + r) * 16 + ln] = (_Float16)v[r];
            sm = smn;
        }

        // final L2 normalize + chunk map for stageB
        float ss = 0.f;
#pragma unroll
        for (int r = 0; r < 4; ++r) ss += v[r] * v[r];
#pragma unroll
        for (int off = 1; off < 64; off <<= 1) ss += __shfl_xor(ss, off);
        const float sl = 1.0f / (sqrtf(ss) + 1e-30f);
        const int cabs = ((row0 & 2047) >> 5) + cblk;
        float* qo = qout + ((size_t)(dirw * SS + seq) * Cn + cabs) * 256;
#pragma unroll
        for (int r = 0; r < 4; ++r)
            qo[(q * 4 + r) * 16 + ln] = v[r] * sl;
    }
}

// ---------------- Stage B: cross-chunk vector propagation (r3-proven) ---------------------
__global__ __launch_bounds__(64) void stageB_kernel(const float* __restrict__ q,
                                                    float* __restrict__ vs, int SS)
{
    const int lane = threadIdx.x & 63;
    const int i = lane & 15;
    const int chain = blockIdx.x;
    const int dir = (chain >= SS) ? 1 : 0;
    const int seq = chain - dir * SS;
    const float* qb = q + (size_t)(dir * SS + seq) * Cn * 256;
    float* vb = vs + (size_t)(dir * SS + seq) * Cn * 16;

    float myw = (i == 0) ? 1.0f : 0.0f;
    float wv[16];
#pragma unroll
    for (int k2 = 0; k2 < 16; ++k2) wv[k2] = (k2 == 0) ? 1.0f : 0.0f;

    int cc = dir ? (Cn - 1) : 0;
    const float* Qp = qb + (size_t)cc * 256 + i * 16;
    float4 q0 = *(const float4*)(Qp + 0);
    float4 q1 = *(const float4*)(Qp + 4);
    float4 q2 = *(const float4*)(Qp + 8);
    float4 q3 = *(const float4*)(Qp + 12);

    for (int s = 0; s < Cn; ++s) {
        vb[cc * 16 + i] = myw;
        float nv = q0.x*wv[0] + q0.y*wv[1] + q0.z*wv[2] + q0.w*wv[3]
                 + q1.x*wv[4] + q1.y*wv[5] + q1.z*wv[6] + q1.w*wv[7]
                 + q2.x*wv[8] + q2.y*wv[9] + q2.z*wv[10] + q2.w*wv[11]
                 + q3.x*wv[12] + q3.y*wv[13] + q3.z*wv[14] + q3.w*wv[15];
        if (s + 1 < Cn) {                       // prefetch next chunk's Q
            const int ccn = dir ? (Cn - 2 - s) : (s + 1);
            const float* Qn = qb + (size_t)ccn * 256 + i * 16;
            q0 = *(const float4*)(Qn + 0);
            q1 = *(const float4*)(Qn + 4);
            q2 = *(const float4*)(Qn + 8);
            q3 = *(const float4*)(Qn + 12);
        }
        float s2 = nv * nv;
        s2 += __shfl_xor(s2, 1); s2 += __shfl_xor(s2, 2);
        s2 += __shfl_xor(s2, 4); s2 += __shfl_xor(s2, 8);
        const float wn = nv / (sqrtf(s2) + 1e-20f);
        myw = wn;
#pragma unroll
        for (int k2 = 0; k2 < 16; ++k2) wv[k2] = __shfl(wn, (lane & 48) | k2);
        cc = dir ? (Cn - 2 - s) : (s + 1);
    }
}

// ---------------- Stage C2: parallel replay x_t = normalize(P_t . v_start) ----------------
__global__ __launch_bounds__(256) void stageC2_kernel(const float* __restrict__ m,
                                                      const float* __restrict__ vs,
                                                      _Float16* __restrict__ x, int SS)
{
    const int tid = threadIdx.x;
    const int wave = tid >> 6, lane = tid & 63;
    const int dsc = blockIdx.x * 4 + wave;        // (dir*SS + seq)*Cn + c
    const int dirseq = dsc >> 6, c = dsc & (Cn - 1);
    const int dir = (dirseq >= SS) ? 1 : 0;
    const int seq = dirseq - dir * SS;
    const int bbl = seq >> 4, h = seq & 15;
    const _Float16* Pp = (const _Float16*)((const char*)m
                       + ((size_t)seq * Tdim + c * Ln) * 1024 + dir * 512);
    const float* vp = vs + (size_t)dsc * 16;

    float v[16];
#pragma unroll
    for (int k = 0; k < 16; ++k) v[k] = vp[k];    // wave-uniform -> broadcast loads

    const int tt = lane >> 4, j = lane & 15;
    const int t0 = c * Ln;
#pragma unroll
    for (int g = 0; g < 8; ++g) {
        const int s = g * 4 + tt;
        const _Float16* pr = Pp + (size_t)s * 512 + j * 16;   // slot stride 1024 B = 512 f16
        const f16x8 p0 = *(const f16x8*)(pr);
        const f16x8 p1 = *(const f16x8*)(pr + 8);
        float nv = 0.f;
#pragma unroll
        for (int k = 0; k < 8; ++k) nv += (float)p0[k] * v[k];
#pragma unroll
        for (int k = 0; k < 8; ++k) nv += (float)p1[k] * v[k + 8];
        float s2 = nv * nv;
        s2 += __shfl_xor(s2, 1); s2 += __shfl_xor(s2, 2);
        s2 += __shfl_xor(s2, 4); s2 += __shfl_xor(s2, 8);
        const float vn = nv / (sqrtf(s2) + 1e-6f);   // reference VEC_EPS semantics
        const int t = t0 + s;                        // slot t holds prefix for output t (both dirs)
        x[(((size_t)bbl * Tdim + t) * NHd + h) * 32 + dir * 16 + j] = (_Float16)vn;
    }
}

// ---------------- GEMM2: 256x256 tile, K=512, same 8-phase counted-vmcnt pipeline ---------
__global__ __launch_bounds__(512, 2) void gemm2_8ph(const _Float16* __restrict__ A,
                                                    const _Float16* __restrict__ BT,
                                                    const float* __restrict__ bias,
                                                    float* __restrict__ out, int row0p)
{
    __shared__ __align__(16) _Float16 sAB[4][256 * 64];   // [0..1]=A dbuf, [2..3]=B dbuf
    const int tid = threadIdx.x;
    const int lane = tid & 63;
    const int wid = tid >> 6;
    const int wm = wid >> 2, wn = wid & 3;
    const int q = lane >> 4, ln = lane & 15;
    const int col0 = blockIdx.x * 256;
    const int row0 = blockIdx.y * 256;

    const char* Ab = (const char*)A  + (size_t)row0 * KB2;
    const char* Bb = (const char*)BT + (size_t)col0 * KB2;

    auto stage_chunk = [&](const char* g, int fr, int kt, char* ldsbase) {
        const int rr = tid >> 3;
        const int cb = (tid & 7) << 4;
        const char* src = g + (size_t)(fr + rr) * KB2 + (size_t)kt * 128 + (cb ^ ((rr & 7) << 4));
        char* dst = ldsbase + ((tid >> 6) << 10);
        __builtin_amdgcn_global_load_lds((gvoid_t*)src, (lvoid_t*)dst, 16, 0, 0);
    };
    auto stageA2g = [&](int b, int t, int h) {
        stage_chunk(Ab, h * 64,       t, (char*)&sAB[b][0] + (size_t)(h * 64) * 128);
        stage_chunk(Ab, 128 + h * 64, t, (char*)&sAB[b][0] + (size_t)(128 + h * 64) * 128);
    };
    auto stageB2 = [&](int b, int t, int h) {
        stage_chunk(Bb, h * 128,      t, (char*)&sAB[2 + b][0] + (size_t)(h * 128) * 128);
        stage_chunk(Bb, h * 128 + 64, t, (char*)&sAB[2 + b][0] + (size_t)(h * 128 + 64) * 128);
    };
    auto readA = [&](int b, int mf, int ks) -> f16x8 {
        const int r = wm * 128 + mf * 16 + ln;
        return *(const f16x8*)((const char*)&sAB[b][0] + r * 128 + ((ks * 64 + q * 16) ^ ((r & 7) << 4)));
    };
    auto readB = [&](int b, int nt, int ks) -> f16x8 {
        const int r = wn * 64 + nt * 16 + ln;
        return *(const f16x8*)((const char*)&sAB[2 + b][0] + r * 128 + ((ks * 64 + q * 16) ^ ((r & 7) << 4)));
    };

    stageB2(0, 0, 0); stageB2(0, 0, 1); stageA2g(0, 0, 0); stageA2g(0, 0, 1);
    stageB2(1, 1, 0); stageB2(1, 1, 1); stageA2g(1, 1, 0);

    f32x4 acc[8][4];
    const f32x4 z4 = {0.f, 0.f, 0.f, 0.f};
#pragma unroll
    for (int mf = 0; mf < 8; ++mf)
#pragma unroll
        for (int nt = 0; nt < 4; ++nt) acc[mf][nt] = z4;

    asm volatile("s_waitcnt vmcnt(6)" ::: "memory");
    asm volatile("s_barrier" ::: "memory");

    f16x8 af[2][2];
    f16x8 bf[4][2];

#pragma unroll 1
    for (int it = 0; it < 4; ++it) {              // K = 512 -> 8 tiles of 64 -> 4 iters
        const int t0 = it * 2;
        const bool notlast = (it != 3);
        PHASE(0, 0, (stageA2g(1, t0 + 1, 1)), 0);
        PHASE(0, 1, (notlast ? stageB2(0, t0 + 2, 0) : (void)0), 0);
        PHASE(0, 2, (notlast ? stageB2(0, t0 + 2, 1) : (void)0), 0);
        PHASE(0, 3, (notlast ? stageA2g(0, t0 + 2, 0) : (void)0), 1);
        PHASE(1, 0, (notlast ? stageA2g(0, t0 + 2, 1) : (void)0), 0);
        PHASE(1, 1, (notlast ? stageB2(1, t0 + 3, 0) : (void)0), 0);
        PHASE(1, 2, (notlast ? stageB2(1, t0 + 3, 1) : (void)0), 0);
        PHASE(1, 3, (notlast ? stageA2g(1, t0 + 3, 0) : (void)0), 1);
    }

#pragma unroll
    for (int nt = 0; nt < 4; ++nt) {
        const int c = col0 + wn * 64 + nt * 16 + ln;
        const float bv = bias[c];
#pragma unroll
        for (int mf = 0; mf < 8; ++mf) {
#pragma unroll
            for (int r = 0; r < 4; ++r) {
                const int row = row0 + wm * 128 + mf * 16 + q * 4 + r;
                float v = acc[mf][nt][r] + bv;
                v = 0.5f * v * (1.0f + erff(v * 0.70710678118654752f));
                out[(size_t)(row0p + row) * 1024 + c] = v;
            }
        }
    }
}

extern "C" void kernel_launch(void* const* d_in, const int* in_sizes, int n_in,
                              void* d_out, int out_size, void* d_ws, size_t ws_size,
                              hipStream_t stream)
{
    const float* hs    = (const float*)d_in[0];
    const float* W_mat = (const float*)d_in[1];
    const float* b_mat = (const float*)d_in[2];
    const float* W_out = (const float*)d_in[3];
    const float* b_out = (const float*)d_in[4];
    float* out = (float*)d_out;

    // layout: W2T(1M) Bcat(24M) | per bb-group: m 32M (f16 prefixes, written by gemm1) |
    //         qx 2M (q f32 / x f16 aliased) | Acat 12M | vs 128K
    // nbb = 4 (L3-residency A/B vs r7's 8): per-pass working set m 128M + Ac 48M + Bc 24M
    // + qx/x/vs ~ 240 MB <= 256 MB Infinity Cache -> P written by gemm1 stays L3-resident
    // for stageC2's read, and pass-2 gemm1 overwrites the same m buffer in-cache.
    const size_t per_bb = (32ull << 20) + (2ull << 20) + (12ull << 20) + (128ull << 10);
    const size_t wbase  = 25ull << 20;
    int nbb = 4;
    while (nbb > 1 && ws_size < wbase + (size_t)nbb * per_bb) nbb >>= 1;

    char* base = (char*)d_ws;
    _Float16* W2T = (_Float16*)base;
    _Float16* Bc  = (_Float16*)(base + (1ull << 20));
    size_t off = wbase;
    float* m  = (float*)(base + off);  off += (size_t)nbb * (32ull << 20);
    float* qx = (float*)(base + off);  off += (size_t)nbb * (2ull << 20);
    _Float16* Ac = (_Float16*)(base + off); off += (size_t)nbb * (12ull << 20);
    float* vs = (float*)(base + off);

    conv_B_kernel<<<dim3(128, 32), 256, 0, stream>>>(W_mat, Bc);
    conv_W2T_kernel<<<dim3(32, 16), 256, 0, stream>>>(W_out, W2T);

    for (int bb0 = 0; bb0 < 8; bb0 += nbb) {
        const int row0 = bb0 * Tdim;
        const int SS = nbb * 16;
        conv_A_kernel<<<nbb * 1024, 256, 0, stream>>>(hs + (size_t)row0 * HIDd, Ac);
        gemm1_8ph<<<dim3(16, nbb * 8), 512, 0, stream>>>(Ac, Bc, b_mat, m, qx, SS);
        stageB_kernel<<<2 * SS, 64, 0, stream>>>(qx, vs, SS);
        stageC2_kernel<<<SS * Cn / 2, 256, 0, stream>>>(m, vs, (_Float16*)qx, SS);
        gemm2_8ph<<<dim3(4, nbb * 8), 512, 0, stream>>>((_Float16*)qx, W2T, b_out, out, row0);
    }
}